// Round 7
// baseline (261.436 us; speedup 1.0000x reference)
//
#include <hip/hip_runtime.h>
#include <hip/hip_bf16.h>
#include <cmath>

#define NH   12
#define HD   64
#define HID  768
#define NB   2
#define SEQL 2048
#define ROWS 4096   // NB*SEQL
#define OUTW 1536   // NH*HD*2

static constexpr float NEGBIG = 1000000000000.0f;

typedef __attribute__((ext_vector_type(4)))  float f32x4;
typedef __attribute__((ext_vector_type(8)))  short short8;
typedef __attribute__((ext_vector_type(16))) float f32x16;

__device__ __forceinline__ unsigned short f2bf(float f) {
    unsigned int u = __builtin_bit_cast(unsigned int, f);
    u += 0x7FFFu + ((u >> 16) & 1u);   // round-to-nearest-even
    return (unsigned short)(u >> 16);
}

// ---- K0: fused prep: convert X, convert W (f32->bf16), build rope table ----
#define XQ (ROWS * HID / 4)          // 786432 float4 groups
#define WQ (OUTW * HID / 4)          // 294912
#define RQ (SEQL * 32)               // 65536
__global__ void k_prep(const float* __restrict__ X, const float* __restrict__ W,
                       unsigned short* __restrict__ Xbf, unsigned short* __restrict__ Wbf,
                       float2* __restrict__ rtab) {
    int i = blockIdx.x * blockDim.x + threadIdx.x;
    if (i < XQ + WQ) {
        const float* src = (i < XQ) ? X : W;
        unsigned short* dst = (i < XQ) ? Xbf : Wbf;
        int k = (i < XQ) ? i : i - XQ;
        float4 v = reinterpret_cast<const float4*>(src)[k];
        ushort4 o;
        o.x = f2bf(v.x); o.y = f2bf(v.y); o.z = f2bf(v.z); o.w = f2bf(v.w);
        reinterpret_cast<ushort4*>(dst)[k] = o;
    } else if (i < XQ + WQ + RQ) {
        int idx = i - (XQ + WQ);
        int n = idx >> 5, d = idx & 31;
        float theta = exp2f(-(float)d * (13.287712379549449f / 32.0f)); // 10000^(-d/32)
        float ang = (float)n * theta;
        rtab[idx] = make_float2(sinf(ang), cosf(ang));
    }
}

// ---- K1: projection GEMM (bf16 MFMA, 128x128 tile, 2x2 acc/wave) + bias + RoPE ----
__global__ __launch_bounds__(256) void k_proj_rope(
    const unsigned short* __restrict__ Xbf,   // [4096][768] bf16
    const unsigned short* __restrict__ Wbf,   // [1536][768] bf16
    const float*  __restrict__ bias,          // [1536]
    const float2* __restrict__ rtab,          // [2048][32]
    unsigned short* __restrict__ Qbf,         // [2][12][2048][64] bf16
    unsigned short* __restrict__ Kbf)
{
    const int head = blockIdx.x;       // 0..11
    const int row0 = blockIdx.y * 128; // global row base in [0,4096)
    const int tid  = threadIdx.x;
    const int lane = tid & 63;
    const int w    = tid >> 6;
    const int wr = w & 1, wc = w >> 1;
    const int l31 = lane & 31, lhi = lane >> 5;

    f32x16 acc[2][2];
#pragma unroll
    for (int i = 0; i < 2; ++i)
#pragma unroll
        for (int j = 0; j < 2; ++j)
#pragma unroll
            for (int r = 0; r < 16; ++r) acc[i][j][r] = 0.0f;

    const int o0 = head * 128 + wc * 64;
    const unsigned short* A0 = Xbf + (size_t)(row0 + wr * 64 + l31) * HID + 8 * lhi;
    const unsigned short* B0 = Wbf + (size_t)(o0 + l31) * HID + 8 * lhi;

#pragma unroll 4
    for (int kk = 0; kk < HID; kk += 16) {
        short8 a0 = *reinterpret_cast<const short8*>(A0 + kk);
        short8 a1 = *reinterpret_cast<const short8*>(A0 + 32 * HID + kk);
        short8 b0 = *reinterpret_cast<const short8*>(B0 + kk);
        short8 b1 = *reinterpret_cast<const short8*>(B0 + 32 * HID + kk);
        acc[0][0] = __builtin_amdgcn_mfma_f32_32x32x16_bf16(a0, b0, acc[0][0], 0, 0, 0);
        acc[0][1] = __builtin_amdgcn_mfma_f32_32x32x16_bf16(a0, b1, acc[0][1], 0, 0, 0);
        acc[1][0] = __builtin_amdgcn_mfma_f32_32x32x16_bf16(a1, b0, acc[1][0], 0, 0, 0);
        acc[1][1] = __builtin_amdgcn_mfma_f32_32x32x16_bf16(a1, b1, acc[1][1], 0, 0, 0);
    }

    // RoPE epilogue in two 64-row slabs. hs cols: 0..63 = q, 64..127 = k.
    __shared__ float hs[64][132];
    for (int s = 0; s < 2; ++s) {
        if (wr == s) {
#pragma unroll
            for (int i = 0; i < 2; ++i)
#pragma unroll
                for (int j = 0; j < 2; ++j)
#pragma unroll
                    for (int r = 0; r < 16; ++r) {
                        int rr = (r & 3) + 8 * (r >> 2) + 4 * lhi;  // 0..31
                        hs[i * 32 + rr][wc * 64 + j * 32 + l31] = acc[i][j][r];
                    }
        }
        __syncthreads();
        // 64 rows x 32 pairs x 2 (q,k) = 4096 ushort2 items, 16 per thread
#pragma unroll 4
        for (int it = 0; it < 16; ++it) {
            int f   = tid + 256 * it;    // 0..4095
            int row = f >> 6;            // 0..63
            int u   = f & 63;
            int isK = u >> 5;
            int dp  = u & 31;            // pair index
            int d0  = 2 * dp, d1 = d0 + 1;
            int cb  = isK * 64;
            int grow = row0 + s * 64 + row;
            int bI = grow >> 11;
            int n  = grow & 2047;
            float2 sc = rtab[n * 32 + dp];
            float v0 = hs[row][cb + d0] + bias[head * 128 + cb + d0];
            float v1 = hs[row][cb + d1] + bias[head * 128 + cb + d1];
            int p0 = (d0 < 32) ? (2 * d0 + 1) : (2 * d0 - 64);
            int p1 = (d1 < 32) ? (2 * d1 + 1) : (2 * d1 - 64);
            float pv0 = hs[row][cb + p0] + bias[head * 128 + cb + p0];
            float pv1 = hs[row][cb + p1] + bias[head * 128 + cb + p1];
            float sg0 = (d0 < 32) ? -1.0f : 1.0f;
            float sg1 = (d1 < 32) ? -1.0f : 1.0f;
            ushort2 st;
            st.x = f2bf(v0 * sc.y + sg0 * pv0 * sc.x);
            st.y = f2bf(v1 * sc.y + sg1 * pv1 * sc.x);
            unsigned short* dst = isK ? (unsigned short*)Kbf : (unsigned short*)Qbf;
            size_t idx = ((size_t)(bI * NH + head) * SEQL + n) * HD + d0;
            *reinterpret_cast<ushort2*>(dst + idx) = st;
        }
        __syncthreads();
    }
}

// ---- K2: logits = QK^T, mask + tril + scale, f32 out. 128x128 tile/block ----
// 1D grid with XCD-bijective swizzle: 6144 = 8 XCDs * 768; each XCD owns 3 bh.
__global__ __launch_bounds__(256) void k_logits(
    const unsigned short* __restrict__ Qbf,
    const unsigned short* __restrict__ Kbf,
    const int* __restrict__ mask,    // [2][2048]
    float* __restrict__ out)         // [2][12][2048][2048]
{
    const int bid = blockIdx.x;
    const int newbid = (bid & 7) * 768 + (bid >> 3);
    const int bh = newbid >> 8;
    const int t  = newbid & 255;
    const int nt = t >> 4, mt = t & 15;
    const int bI = bh / NH;
    const int tid = threadIdx.x;
    float* outbase = out + (size_t)bh * SEQL * SEQL;

    if (mt < nt) {
        // Tile entirely strictly-below-diagonal: output independent of logits.
        const int cg = tid & 31;        // column group -> 4 consecutive cols
        const int r0 = tid >> 5;        // 0..7
        const int m0 = mt * 128 + cg * 4;
        const int4 mi = *reinterpret_cast<const int4*>(mask + bI * SEQL + m0);
        f32x4 v;
        v.x = ((float)mi.x - 2.0f) * (NEGBIG * 0.125f);
        v.y = ((float)mi.y - 2.0f) * (NEGBIG * 0.125f);
        v.z = ((float)mi.z - 2.0f) * (NEGBIG * 0.125f);
        v.w = ((float)mi.w - 2.0f) * (NEGBIG * 0.125f);
        float* ob = outbase + (size_t)(nt * 128) * SEQL + m0;
#pragma unroll
        for (int j = 0; j < 16; ++j) {
            int row = r0 + 8 * j;       // 0..127
            __builtin_nontemporal_store(v, reinterpret_cast<f32x4*>(ob + (size_t)row * SEQL));
        }
        return;
    }

    const int lane = tid & 63;
    const int w = tid >> 6;
    const int rowHalf = w & 1, colHalf = w >> 1;
    const int l31 = lane & 31, lhi = lane >> 5;
    const int n0 = nt * 128 + rowHalf * 64;
    const int m0 = mt * 128 + colHalf * 64;

    f32x16 acc[2][2];
#pragma unroll
    for (int i = 0; i < 2; ++i)
#pragma unroll
        for (int j = 0; j < 2; ++j)
#pragma unroll
            for (int r = 0; r < 16; ++r) acc[i][j][r] = 0.0f;

    const unsigned short* Aq = Qbf + ((size_t)bh * SEQL + n0 + l31) * HD + 8 * lhi;
    const unsigned short* Bk = Kbf + ((size_t)bh * SEQL + m0 + l31) * HD + 8 * lhi;
#pragma unroll
    for (int t2 = 0; t2 < 4; ++t2) {
        short8 a0 = *reinterpret_cast<const short8*>(Aq + 16 * t2);
        short8 a1 = *reinterpret_cast<const short8*>(Aq + 32 * HD + 16 * t2);
        short8 b0 = *reinterpret_cast<const short8*>(Bk + 16 * t2);
        short8 b1 = *reinterpret_cast<const short8*>(Bk + 32 * HD + 16 * t2);
        acc[0][0] = __builtin_amdgcn_mfma_f32_32x32x16_bf16(a0, b0, acc[0][0], 0, 0, 0);
        acc[0][1] = __builtin_amdgcn_mfma_f32_32x32x16_bf16(a0, b1, acc[0][1], 0, 0, 0);
        acc[1][0] = __builtin_amdgcn_mfma_f32_32x32x16_bf16(a1, b0, acc[1][0], 0, 0, 0);
        acc[1][1] = __builtin_amdgcn_mfma_f32_32x32x16_bf16(a1, b1, acc[1][1], 0, 0, 0);
    }

    // LDS-transpose epilogue: two 32-row slabs (i = 0,1), f32x4 NT stores.
    __shared__ float tl[64][128];   // 32 KB
#pragma unroll
    for (int i = 0; i < 2; ++i) {
#pragma unroll
        for (int j = 0; j < 2; ++j) {
#pragma unroll
            for (int r = 0; r < 16; ++r) {
                int rr = (r & 3) + 8 * (r >> 2) + 4 * lhi;    // 0..31
                tl[rowHalf * 32 + rr][colHalf * 64 + j * 32 + l31] = acc[i][j][r];
            }
        }
        __syncthreads();
        // 64 rows x 128 cols = 2048 f32x4; 256 threads x 8 iters
#pragma unroll
        for (int it = 0; it < 8; ++it) {
            int f   = tid + 256 * it;      // 0..2047
            int lr  = f >> 5;              // 0..63
            int cg  = f & 31;              // 0..31 -> 4 cols
            int grow = nt * 128 + (lr >> 5) * 64 + i * 32 + (lr & 31);
            int gcol = mt * 128 + cg * 4;
            const int4 mi = *reinterpret_cast<const int4*>(mask + bI * SEQL + gcol);
            f32x4 v = *reinterpret_cast<const f32x4*>(&tl[lr][cg * 4]);
            float pads[4] = {(float)mi.x, (float)mi.y, (float)mi.z, (float)mi.w};
#pragma unroll
            for (int e = 0; e < 4; ++e) {
                float vv = v[e] * pads[e] - (1.0f - pads[e]) * NEGBIG;
                if (gcol + e < grow) vv -= NEGBIG;
                v[e] = vv * 0.125f;
            }
            __builtin_nontemporal_store(v, reinterpret_cast<f32x4*>(outbase + (size_t)grow * SEQL + gcol));
        }
        __syncthreads();
    }
}

extern "C" void kernel_launch(void* const* d_in, const int* in_sizes, int n_in,
                              void* d_out, int out_size, void* d_ws, size_t ws_size,
                              hipStream_t stream) {
    const float* x    = (const float*)d_in[0];
    const int*   mask = (const int*)d_in[1];
    const float* W    = (const float*)d_in[2];
    const float* bias = (const float*)d_in[3];
    float* out = (float*)d_out;

    char* ws = (char*)d_ws;
    unsigned short* Xbf = (unsigned short*)(ws);                 // 6,291,456 B
    unsigned short* Wbf = (unsigned short*)(ws + 6291456);       // 2,359,296 B
    unsigned short* Qbf = (unsigned short*)(ws + 8650752);       // 6,291,456 B
    unsigned short* Kbf = (unsigned short*)(ws + 14942208);      // 6,291,456 B
    float2*         rtab = (float2*)(ws + 21233664);             //   524,288 B

    const int prep_items = XQ + WQ + RQ;                         // 1,146,880
    k_prep<<<dim3((prep_items + 255) / 256), dim3(256), 0, stream>>>(x, W, Xbf, Wbf, rtab);
    // ATTRIBUTION PROBE #2: K1 twice (idempotent). K2 twice, unchanged from R5/R6
    // so warm-K2 = 71.4 µs is a known constant.
    // warm K1 = total - 136.3 - 71.4. Remove both duplicates next round.
    k_proj_rope<<<dim3(12, 32), dim3(256), 0, stream>>>(Xbf, Wbf, bias, rtab, Qbf, Kbf);
    k_proj_rope<<<dim3(12, 32), dim3(256), 0, stream>>>(Xbf, Wbf, bias, rtab, Qbf, Kbf);
    k_logits<<<dim3(6144), dim3(256), 0, stream>>>(Qbf, Kbf, mask, out);
    k_logits<<<dim3(6144), dim3(256), 0, stream>>>(Qbf, Kbf, mask, out);
}

// Round 8
// 136.640 us; speedup vs baseline: 1.9133x; 1.9133x over previous
//
#include <hip/hip_runtime.h>
#include <hip/hip_bf16.h>
#include <cmath>

#define NH   12
#define HD   64
#define HID  768
#define NB   2
#define SEQL 2048
#define ROWS 4096   // NB*SEQL
#define OUTW 1536   // NH*HD*2

static constexpr float NEGBIG = 1000000000000.0f;

typedef __attribute__((ext_vector_type(4)))  float f32x4;
typedef __attribute__((ext_vector_type(8)))  short short8;
typedef __attribute__((ext_vector_type(16))) float f32x16;

__device__ __forceinline__ unsigned short f2bf(float f) {
    unsigned int u = __builtin_bit_cast(unsigned int, f);
    u += 0x7FFFu + ((u >> 16) & 1u);   // round-to-nearest-even
    return (unsigned short)(u >> 16);
}

// ---- K0: fused prep: convert X, convert W (f32->bf16), build rope table ----
#define XQ (ROWS * HID / 4)          // 786432 float4 groups
#define WQ (OUTW * HID / 4)          // 294912
#define RQ (SEQL * 32)               // 65536
__global__ void k_prep(const float* __restrict__ X, const float* __restrict__ W,
                       unsigned short* __restrict__ Xbf, unsigned short* __restrict__ Wbf,
                       float2* __restrict__ rtab) {
    int i = blockIdx.x * blockDim.x + threadIdx.x;
    if (i < XQ + WQ) {
        const float* src = (i < XQ) ? X : W;
        unsigned short* dst = (i < XQ) ? Xbf : Wbf;
        int k = (i < XQ) ? i : i - XQ;
        float4 v = reinterpret_cast<const float4*>(src)[k];
        ushort4 o;
        o.x = f2bf(v.x); o.y = f2bf(v.y); o.z = f2bf(v.z); o.w = f2bf(v.w);
        reinterpret_cast<ushort4*>(dst)[k] = o;
    } else if (i < XQ + WQ + RQ) {
        int idx = i - (XQ + WQ);
        int n = idx >> 5, d = idx & 31;
        float theta = exp2f(-(float)d * (13.287712379549449f / 32.0f)); // 10000^(-d/32)
        float ang = (float)n * theta;
        rtab[idx] = make_float2(sinf(ang), cosf(ang));
    }
}

// ---- K1: projection GEMM (bf16 MFMA, 128x128 tile, 2x2 acc/wave) + bias + RoPE ----
// 1D grid 384 = 8 XCDs x 48, XCD-bijective: XCD c owns newbid in [48c, 48c+48)
// = 4 row-slabs x 12 heads -> per-XCD working set A(784KB)+W(2.25MB) < 4MB L2.
__global__ __launch_bounds__(256) void k_proj_rope(
    const unsigned short* __restrict__ Xbf,   // [4096][768] bf16
    const unsigned short* __restrict__ Wbf,   // [1536][768] bf16
    const float*  __restrict__ bias,          // [1536]
    const float2* __restrict__ rtab,          // [2048][32]
    unsigned short* __restrict__ Qbf,         // [2][12][2048][64] bf16
    unsigned short* __restrict__ Kbf)
{
    const int bid = blockIdx.x;                     // 0..383
    const int newbid = (bid & 7) * 48 + (bid >> 3); // bijective: 384 = 8*48
    const int slab = newbid / 12;                   // 0..31
    const int head = newbid % 12;                   // 0..11
    const int row0 = slab * 128;
    const int tid  = threadIdx.x;
    const int lane = tid & 63;
    const int w    = tid >> 6;
    const int wr = w & 1, wc = w >> 1;
    const int l31 = lane & 31, lhi = lane >> 5;

    f32x16 acc[2][2];
#pragma unroll
    for (int i = 0; i < 2; ++i)
#pragma unroll
        for (int j = 0; j < 2; ++j)
#pragma unroll
            for (int r = 0; r < 16; ++r) acc[i][j][r] = 0.0f;

    const int o0 = head * 128 + wc * 64;
    const unsigned short* A0 = Xbf + (size_t)(row0 + wr * 64 + l31) * HID + 8 * lhi;
    const unsigned short* B0 = Wbf + (size_t)(o0 + l31) * HID + 8 * lhi;

#pragma unroll 4
    for (int kk = 0; kk < HID; kk += 16) {
        short8 a0 = *reinterpret_cast<const short8*>(A0 + kk);
        short8 a1 = *reinterpret_cast<const short8*>(A0 + 32 * HID + kk);
        short8 b0 = *reinterpret_cast<const short8*>(B0 + kk);
        short8 b1 = *reinterpret_cast<const short8*>(B0 + 32 * HID + kk);
        acc[0][0] = __builtin_amdgcn_mfma_f32_32x32x16_bf16(a0, b0, acc[0][0], 0, 0, 0);
        acc[0][1] = __builtin_amdgcn_mfma_f32_32x32x16_bf16(a0, b1, acc[0][1], 0, 0, 0);
        acc[1][0] = __builtin_amdgcn_mfma_f32_32x32x16_bf16(a1, b0, acc[1][0], 0, 0, 0);
        acc[1][1] = __builtin_amdgcn_mfma_f32_32x32x16_bf16(a1, b1, acc[1][1], 0, 0, 0);
    }

    // RoPE epilogue in two 64-row slabs. hs cols: 0..63 = q, 64..127 = k.
    __shared__ float hs[64][132];
    for (int s = 0; s < 2; ++s) {
        if (wr == s) {
#pragma unroll
            for (int i = 0; i < 2; ++i)
#pragma unroll
                for (int j = 0; j < 2; ++j)
#pragma unroll
                    for (int r = 0; r < 16; ++r) {
                        int rr = (r & 3) + 8 * (r >> 2) + 4 * lhi;  // 0..31
                        hs[i * 32 + rr][wc * 64 + j * 32 + l31] = acc[i][j][r];
                    }
        }
        __syncthreads();
        // 64 rows x 32 pairs x 2 (q,k) = 4096 ushort2 items, 16 per thread
#pragma unroll 4
        for (int it = 0; it < 16; ++it) {
            int f   = tid + 256 * it;    // 0..4095
            int row = f >> 6;            // 0..63
            int u   = f & 63;
            int isK = u >> 5;
            int dp  = u & 31;            // pair index
            int d0  = 2 * dp, d1 = d0 + 1;
            int cb  = isK * 64;
            int grow = row0 + s * 64 + row;
            int bI = grow >> 11;
            int n  = grow & 2047;
            float2 sc = rtab[n * 32 + dp];
            float v0 = hs[row][cb + d0] + bias[head * 128 + cb + d0];
            float v1 = hs[row][cb + d1] + bias[head * 128 + cb + d1];
            int p0 = (d0 < 32) ? (2 * d0 + 1) : (2 * d0 - 64);
            int p1 = (d1 < 32) ? (2 * d1 + 1) : (2 * d1 - 64);
            float pv0 = hs[row][cb + p0] + bias[head * 128 + cb + p0];
            float pv1 = hs[row][cb + p1] + bias[head * 128 + cb + p1];
            float sg0 = (d0 < 32) ? -1.0f : 1.0f;
            float sg1 = (d1 < 32) ? -1.0f : 1.0f;
            ushort2 st;
            st.x = f2bf(v0 * sc.y + sg0 * pv0 * sc.x);
            st.y = f2bf(v1 * sc.y + sg1 * pv1 * sc.x);
            unsigned short* dst = isK ? (unsigned short*)Kbf : (unsigned short*)Qbf;
            size_t idx = ((size_t)(bI * NH + head) * SEQL + n) * HD + d0;
            *reinterpret_cast<ushort2*>(dst + idx) = st;
        }
        __syncthreads();
    }
}

// ---- K2: logits = QK^T, mask + tril + scale, f32 out. 128x128 tile/block ----
// 1D grid with XCD-bijective swizzle: 6144 = 8 XCDs * 768; each XCD owns 3 bh.
__global__ __launch_bounds__(256) void k_logits(
    const unsigned short* __restrict__ Qbf,
    const unsigned short* __restrict__ Kbf,
    const int* __restrict__ mask,    // [2][2048]
    float* __restrict__ out)         // [2][12][2048][2048]
{
    const int bid = blockIdx.x;
    const int newbid = (bid & 7) * 768 + (bid >> 3);
    const int bh = newbid >> 8;
    const int t  = newbid & 255;
    const int nt = t >> 4, mt = t & 15;
    const int bI = bh / NH;
    const int tid = threadIdx.x;
    float* outbase = out + (size_t)bh * SEQL * SEQL;

    if (mt < nt) {
        // Tile entirely strictly-below-diagonal: output independent of logits.
        const int cg = tid & 31;        // column group -> 4 consecutive cols
        const int r0 = tid >> 5;        // 0..7
        const int m0 = mt * 128 + cg * 4;
        const int4 mi = *reinterpret_cast<const int4*>(mask + bI * SEQL + m0);
        f32x4 v;
        v.x = ((float)mi.x - 2.0f) * (NEGBIG * 0.125f);
        v.y = ((float)mi.y - 2.0f) * (NEGBIG * 0.125f);
        v.z = ((float)mi.z - 2.0f) * (NEGBIG * 0.125f);
        v.w = ((float)mi.w - 2.0f) * (NEGBIG * 0.125f);
        float* ob = outbase + (size_t)(nt * 128) * SEQL + m0;
#pragma unroll
        for (int j = 0; j < 16; ++j) {
            int row = r0 + 8 * j;       // 0..127
            __builtin_nontemporal_store(v, reinterpret_cast<f32x4*>(ob + (size_t)row * SEQL));
        }
        return;
    }

    const int lane = tid & 63;
    const int w = tid >> 6;
    const int rowHalf = w & 1, colHalf = w >> 1;
    const int l31 = lane & 31, lhi = lane >> 5;
    const int n0 = nt * 128 + rowHalf * 64;
    const int m0 = mt * 128 + colHalf * 64;

    f32x16 acc[2][2];
#pragma unroll
    for (int i = 0; i < 2; ++i)
#pragma unroll
        for (int j = 0; j < 2; ++j)
#pragma unroll
            for (int r = 0; r < 16; ++r) acc[i][j][r] = 0.0f;

    const unsigned short* Aq = Qbf + ((size_t)bh * SEQL + n0 + l31) * HD + 8 * lhi;
    const unsigned short* Bk = Kbf + ((size_t)bh * SEQL + m0 + l31) * HD + 8 * lhi;
#pragma unroll
    for (int t2 = 0; t2 < 4; ++t2) {
        short8 a0 = *reinterpret_cast<const short8*>(Aq + 16 * t2);
        short8 a1 = *reinterpret_cast<const short8*>(Aq + 32 * HD + 16 * t2);
        short8 b0 = *reinterpret_cast<const short8*>(Bk + 16 * t2);
        short8 b1 = *reinterpret_cast<const short8*>(Bk + 32 * HD + 16 * t2);
        acc[0][0] = __builtin_amdgcn_mfma_f32_32x32x16_bf16(a0, b0, acc[0][0], 0, 0, 0);
        acc[0][1] = __builtin_amdgcn_mfma_f32_32x32x16_bf16(a0, b1, acc[0][1], 0, 0, 0);
        acc[1][0] = __builtin_amdgcn_mfma_f32_32x32x16_bf16(a1, b0, acc[1][0], 0, 0, 0);
        acc[1][1] = __builtin_amdgcn_mfma_f32_32x32x16_bf16(a1, b1, acc[1][1], 0, 0, 0);
    }

    // LDS-transpose epilogue: two 32-row slabs (i = 0,1), f32x4 NT stores.
    __shared__ float tl[64][128];   // 32 KB
#pragma unroll
    for (int i = 0; i < 2; ++i) {
#pragma unroll
        for (int j = 0; j < 2; ++j) {
#pragma unroll
            for (int r = 0; r < 16; ++r) {
                int rr = (r & 3) + 8 * (r >> 2) + 4 * lhi;    // 0..31
                tl[rowHalf * 32 + rr][colHalf * 64 + j * 32 + l31] = acc[i][j][r];
            }
        }
        __syncthreads();
        // 64 rows x 128 cols = 2048 f32x4; 256 threads x 8 iters
#pragma unroll
        for (int it = 0; it < 8; ++it) {
            int f   = tid + 256 * it;      // 0..2047
            int lr  = f >> 5;              // 0..63
            int cg  = f & 31;              // 0..31 -> 4 cols
            int grow = nt * 128 + (lr >> 5) * 64 + i * 32 + (lr & 31);
            int gcol = mt * 128 + cg * 4;
            const int4 mi = *reinterpret_cast<const int4*>(mask + bI * SEQL + gcol);
            f32x4 v = *reinterpret_cast<const f32x4*>(&tl[lr][cg * 4]);
            float pads[4] = {(float)mi.x, (float)mi.y, (float)mi.z, (float)mi.w};
#pragma unroll
            for (int e = 0; e < 4; ++e) {
                float vv = v[e] * pads[e] - (1.0f - pads[e]) * NEGBIG;
                if (gcol + e < grow) vv -= NEGBIG;
                v[e] = vv * 0.125f;
            }
            __builtin_nontemporal_store(v, reinterpret_cast<f32x4*>(outbase + (size_t)grow * SEQL + gcol));
        }
        __syncthreads();
    }
}

extern "C" void kernel_launch(void* const* d_in, const int* in_sizes, int n_in,
                              void* d_out, int out_size, void* d_ws, size_t ws_size,
                              hipStream_t stream) {
    const float* x    = (const float*)d_in[0];
    const int*   mask = (const int*)d_in[1];
    const float* W    = (const float*)d_in[2];
    const float* bias = (const float*)d_in[3];
    float* out = (float*)d_out;

    char* ws = (char*)d_ws;
    unsigned short* Xbf = (unsigned short*)(ws);                 // 6,291,456 B
    unsigned short* Wbf = (unsigned short*)(ws + 6291456);       // 2,359,296 B
    unsigned short* Qbf = (unsigned short*)(ws + 8650752);       // 6,291,456 B
    unsigned short* Kbf = (unsigned short*)(ws + 14942208);      // 6,291,456 B
    float2*         rtab = (float2*)(ws + 21233664);             //   524,288 B

    const int prep_items = XQ + WQ + RQ;                         // 1,146,880
    k_prep<<<dim3((prep_items + 255) / 256), dim3(256), 0, stream>>>(x, W, Xbf, Wbf, rtab);
    k_proj_rope<<<dim3(384), dim3(256), 0, stream>>>(Xbf, Wbf, bias, rtab, Qbf, Kbf);
    k_logits<<<dim3(6144), dim3(256), 0, stream>>>(Qbf, Kbf, mask, out);
}

// Round 9
// 116.186 us; speedup vs baseline: 2.2502x; 1.1760x over previous
//
#include <hip/hip_runtime.h>
#include <hip/hip_bf16.h>
#include <cmath>

#define NH   12
#define HD   64
#define HID  768
#define NB   2
#define SEQL 2048
#define ROWS 4096   // NB*SEQL
#define OUTW 1536   // NH*HD*2

static constexpr float NEGBIG = 1000000000000.0f;

typedef __attribute__((ext_vector_type(4)))  float f32x4;
typedef __attribute__((ext_vector_type(8)))  short short8;
typedef __attribute__((ext_vector_type(16))) float f32x16;

__device__ __forceinline__ unsigned short f2bf(float f) {
    unsigned int u = __builtin_bit_cast(unsigned int, f);
    u += 0x7FFFu + ((u >> 16) & 1u);   // round-to-nearest-even
    return (unsigned short)(u >> 16);
}

// ---- K0: fused prep: convert X, convert W (f32->bf16), build rope table ----
#define XQ (ROWS * HID / 4)          // 786432 float4 groups
#define WQ (OUTW * HID / 4)          // 294912
#define RQ (SEQL * 32)               // 65536
__global__ void k_prep(const float* __restrict__ X, const float* __restrict__ W,
                       unsigned short* __restrict__ Xbf, unsigned short* __restrict__ Wbf,
                       float2* __restrict__ rtab) {
    int i = blockIdx.x * blockDim.x + threadIdx.x;
    if (i < XQ + WQ) {
        const float* src = (i < XQ) ? X : W;
        unsigned short* dst = (i < XQ) ? Xbf : Wbf;
        int k = (i < XQ) ? i : i - XQ;
        float4 v = reinterpret_cast<const float4*>(src)[k];
        ushort4 o;
        o.x = f2bf(v.x); o.y = f2bf(v.y); o.z = f2bf(v.z); o.w = f2bf(v.w);
        reinterpret_cast<ushort4*>(dst)[k] = o;
    } else if (i < XQ + WQ + RQ) {
        int idx = i - (XQ + WQ);
        int n = idx >> 5, d = idx & 31;
        float theta = exp2f(-(float)d * (13.287712379549449f / 32.0f)); // 10000^(-d/32)
        float ang = (float)n * theta;
        rtab[idx] = make_float2(sinf(ang), cosf(ang));
    }
}

// ---- K1: LDS-staged dbuf GEMM (bf16 MFMA, 128x128 tile, BK=64) + bias + RoPE ----
// Staging is COALESCED (8 threads cover one row's 128B) -> fixes the 32-way
// scattered direct-fragment loads of the previous version. XOR slot swizzle
// (slot ^= row&7) applied on BOTH ds_write and ds_read -> ~2 lanes/bank.
__global__ __launch_bounds__(256) void k_proj_rope(
    const unsigned short* __restrict__ Xbf,   // [4096][768] bf16
    const unsigned short* __restrict__ Wbf,   // [1536][768] bf16
    const float*  __restrict__ bias,          // [1536]
    const float2* __restrict__ rtab,          // [2048][32]
    unsigned short* __restrict__ Qbf,         // [2][12][2048][64] bf16
    unsigned short* __restrict__ Kbf)
{
    const int bid = blockIdx.x;                     // 0..383
    const int newbid = (bid & 7) * 48 + (bid >> 3); // bijective: 384 = 8*48
    const int slab = newbid / 12;                   // 0..31
    const int head = newbid % 12;                   // 0..11
    const int row0 = slab * 128;
    const int tid  = threadIdx.x;
    const int lane = tid & 63;
    const int w    = tid >> 6;
    const int wr = w & 1, wc = w >> 1;
    const int l31 = lane & 31, lhi = lane >> 5;
    const int x7  = l31 & 7;

    // 64 KB: A bufs at [0,16K),[16K,32K); B bufs at [32K,48K),[48K,64K) bytes.
    __shared__ __align__(16) unsigned short smem[32768];

    f32x16 acc[2][2];
#pragma unroll
    for (int i = 0; i < 2; ++i)
#pragma unroll
        for (int j = 0; j < 2; ++j)
#pragma unroll
            for (int r = 0; r < 16; ++r) acc[i][j][r] = 0.0f;

    const unsigned short* Abase = Xbf + (size_t)row0 * HID;
    const unsigned short* Bbase = Wbf + (size_t)(head * 128) * HID;

    // per-thread staging coords: idx = tid + 256r -> row = idx>>3, slot s = idx&7
    short8 ga[4], gb[4];
#pragma unroll
    for (int r = 0; r < 4; ++r) {
        int idx = tid + 256 * r, row = idx >> 3, s = idx & 7;
        ga[r] = *reinterpret_cast<const short8*>(Abase + (size_t)row * HID + s * 8);
        gb[r] = *reinterpret_cast<const short8*>(Bbase + (size_t)row * HID + s * 8);
    }
#pragma unroll
    for (int r = 0; r < 4; ++r) {
        int idx = tid + 256 * r, row = idx >> 3, s = idx & 7;
        int ws = s ^ (row & 7);
        *reinterpret_cast<short8*>(smem + row * 64 + ws * 8)         = ga[r];
        *reinterpret_cast<short8*>(smem + 16384 + row * 64 + ws * 8) = gb[r];
    }
    __syncthreads();

    for (int t = 0; t < 12; ++t) {
        const int cur = t & 1;
        if (t < 11) {
            const int kk = (t + 1) * 64;
#pragma unroll
            for (int r = 0; r < 4; ++r) {
                int idx = tid + 256 * r, row = idx >> 3, s = idx & 7;
                ga[r] = *reinterpret_cast<const short8*>(Abase + (size_t)row * HID + kk + s * 8);
                gb[r] = *reinterpret_cast<const short8*>(Bbase + (size_t)row * HID + kk + s * 8);
            }
        }
        const unsigned short* Ab = smem + cur * 8192;
        const unsigned short* Bb = smem + 16384 + cur * 8192;
#pragma unroll
        for (int ks = 0; ks < 4; ++ks) {
            int sl = (ks * 2 + lhi) ^ x7;
            short8 a0 = *reinterpret_cast<const short8*>(Ab + (wr * 64 + l31) * 64      + sl * 8);
            short8 a1 = *reinterpret_cast<const short8*>(Ab + (wr * 64 + 32 + l31) * 64 + sl * 8);
            short8 b0 = *reinterpret_cast<const short8*>(Bb + (wc * 64 + l31) * 64      + sl * 8);
            short8 b1 = *reinterpret_cast<const short8*>(Bb + (wc * 64 + 32 + l31) * 64 + sl * 8);
            acc[0][0] = __builtin_amdgcn_mfma_f32_32x32x16_bf16(a0, b0, acc[0][0], 0, 0, 0);
            acc[0][1] = __builtin_amdgcn_mfma_f32_32x32x16_bf16(a0, b1, acc[0][1], 0, 0, 0);
            acc[1][0] = __builtin_amdgcn_mfma_f32_32x32x16_bf16(a1, b0, acc[1][0], 0, 0, 0);
            acc[1][1] = __builtin_amdgcn_mfma_f32_32x32x16_bf16(a1, b1, acc[1][1], 0, 0, 0);
        }
        if (t < 11) {
            const int nxt = cur ^ 1;
            unsigned short* Aw = smem + nxt * 8192;
            unsigned short* Bw = smem + 16384 + nxt * 8192;
#pragma unroll
            for (int r = 0; r < 4; ++r) {
                int idx = tid + 256 * r, row = idx >> 3, s = idx & 7;
                int ws = s ^ (row & 7);
                *reinterpret_cast<short8*>(Aw + row * 64 + ws * 8) = ga[r];
                *reinterpret_cast<short8*>(Bw + row * 64 + ws * 8) = gb[r];
            }
        }
        __syncthreads();
    }

    // RoPE epilogue in two 64-row slabs, reusing smem as float hs[64][132].
    float (*hs)[132] = reinterpret_cast<float (*)[132]>(smem);
    for (int s = 0; s < 2; ++s) {
        if (wr == s) {
#pragma unroll
            for (int i = 0; i < 2; ++i)
#pragma unroll
                for (int j = 0; j < 2; ++j)
#pragma unroll
                    for (int r = 0; r < 16; ++r) {
                        int rr = (r & 3) + 8 * (r >> 2) + 4 * lhi;  // 0..31
                        hs[i * 32 + rr][wc * 64 + j * 32 + l31] = acc[i][j][r];
                    }
        }
        __syncthreads();
        // 64 rows x 32 pairs x 2 (q,k) = 4096 ushort2 items, 16 per thread
#pragma unroll 4
        for (int it = 0; it < 16; ++it) {
            int f   = tid + 256 * it;    // 0..4095
            int row = f >> 6;            // 0..63
            int u   = f & 63;
            int isK = u >> 5;
            int dp  = u & 31;            // pair index
            int d0  = 2 * dp, d1 = d0 + 1;
            int cb  = isK * 64;
            int grow = row0 + s * 64 + row;
            int bI = grow >> 11;
            int n  = grow & 2047;
            float2 sc = rtab[n * 32 + dp];
            float v0 = hs[row][cb + d0] + bias[head * 128 + cb + d0];
            float v1 = hs[row][cb + d1] + bias[head * 128 + cb + d1];
            int p0 = (d0 < 32) ? (2 * d0 + 1) : (2 * d0 - 64);
            int p1 = (d1 < 32) ? (2 * d1 + 1) : (2 * d1 - 64);
            float pv0 = hs[row][cb + p0] + bias[head * 128 + cb + p0];
            float pv1 = hs[row][cb + p1] + bias[head * 128 + cb + p1];
            float sg0 = (d0 < 32) ? -1.0f : 1.0f;
            float sg1 = (d1 < 32) ? -1.0f : 1.0f;
            ushort2 st;
            st.x = f2bf(v0 * sc.y + sg0 * pv0 * sc.x);
            st.y = f2bf(v1 * sc.y + sg1 * pv1 * sc.x);
            unsigned short* dst = isK ? (unsigned short*)Kbf : (unsigned short*)Qbf;
            size_t idx = ((size_t)(bI * NH + head) * SEQL + n) * HD + d0;
            *reinterpret_cast<ushort2*>(dst + idx) = st;
        }
        __syncthreads();
    }
}

// ---- K2: logits = QK^T, mask + tril + scale, f32 out. 128x128 tile/block ----
// 1D grid with XCD-bijective swizzle: 6144 = 8 XCDs * 768; each XCD owns 3 bh.
__global__ __launch_bounds__(256) void k_logits(
    const unsigned short* __restrict__ Qbf,
    const unsigned short* __restrict__ Kbf,
    const int* __restrict__ mask,    // [2][2048]
    float* __restrict__ out)         // [2][12][2048][2048]
{
    const int bid = blockIdx.x;
    const int newbid = (bid & 7) * 768 + (bid >> 3);
    const int bh = newbid >> 8;
    const int t  = newbid & 255;
    const int nt = t >> 4, mt = t & 15;
    const int bI = bh / NH;
    const int tid = threadIdx.x;
    float* outbase = out + (size_t)bh * SEQL * SEQL;

    if (mt < nt) {
        // Tile entirely strictly-below-diagonal: output independent of logits.
        const int cg = tid & 31;        // column group -> 4 consecutive cols
        const int r0 = tid >> 5;        // 0..7
        const int m0 = mt * 128 + cg * 4;
        const int4 mi = *reinterpret_cast<const int4*>(mask + bI * SEQL + m0);
        f32x4 v;
        v.x = ((float)mi.x - 2.0f) * (NEGBIG * 0.125f);
        v.y = ((float)mi.y - 2.0f) * (NEGBIG * 0.125f);
        v.z = ((float)mi.z - 2.0f) * (NEGBIG * 0.125f);
        v.w = ((float)mi.w - 2.0f) * (NEGBIG * 0.125f);
        float* ob = outbase + (size_t)(nt * 128) * SEQL + m0;
#pragma unroll
        for (int j = 0; j < 16; ++j) {
            int row = r0 + 8 * j;       // 0..127
            __builtin_nontemporal_store(v, reinterpret_cast<f32x4*>(ob + (size_t)row * SEQL));
        }
        return;
    }

    const int lane = tid & 63;
    const int w = tid >> 6;
    const int rowHalf = w & 1, colHalf = w >> 1;
    const int l31 = lane & 31, lhi = lane >> 5;
    const int n0 = nt * 128 + rowHalf * 64;
    const int m0 = mt * 128 + colHalf * 64;

    f32x16 acc[2][2];
#pragma unroll
    for (int i = 0; i < 2; ++i)
#pragma unroll
        for (int j = 0; j < 2; ++j)
#pragma unroll
            for (int r = 0; r < 16; ++r) acc[i][j][r] = 0.0f;

    const unsigned short* Aq = Qbf + ((size_t)bh * SEQL + n0 + l31) * HD + 8 * lhi;
    const unsigned short* Bk = Kbf + ((size_t)bh * SEQL + m0 + l31) * HD + 8 * lhi;
#pragma unroll
    for (int t2 = 0; t2 < 4; ++t2) {
        short8 a0 = *reinterpret_cast<const short8*>(Aq + 16 * t2);
        short8 a1 = *reinterpret_cast<const short8*>(Aq + 32 * HD + 16 * t2);
        short8 b0 = *reinterpret_cast<const short8*>(Bk + 16 * t2);
        short8 b1 = *reinterpret_cast<const short8*>(Bk + 32 * HD + 16 * t2);
        acc[0][0] = __builtin_amdgcn_mfma_f32_32x32x16_bf16(a0, b0, acc[0][0], 0, 0, 0);
        acc[0][1] = __builtin_amdgcn_mfma_f32_32x32x16_bf16(a0, b1, acc[0][1], 0, 0, 0);
        acc[1][0] = __builtin_amdgcn_mfma_f32_32x32x16_bf16(a1, b0, acc[1][0], 0, 0, 0);
        acc[1][1] = __builtin_amdgcn_mfma_f32_32x32x16_bf16(a1, b1, acc[1][1], 0, 0, 0);
    }

    // LDS-transpose epilogue: two 32-row slabs (i = 0,1), f32x4 NT stores.
    __shared__ float tl[64][128];   // 32 KB
#pragma unroll
    for (int i = 0; i < 2; ++i) {
#pragma unroll
        for (int j = 0; j < 2; ++j) {
#pragma unroll
            for (int r = 0; r < 16; ++r) {
                int rr = (r & 3) + 8 * (r >> 2) + 4 * lhi;    // 0..31
                tl[rowHalf * 32 + rr][colHalf * 64 + j * 32 + l31] = acc[i][j][r];
            }
        }
        __syncthreads();
        // 64 rows x 128 cols = 2048 f32x4; 256 threads x 8 iters
#pragma unroll
        for (int it = 0; it < 8; ++it) {
            int f   = tid + 256 * it;      // 0..2047
            int lr  = f >> 5;              // 0..63
            int cg  = f & 31;              // 0..31 -> 4 cols
            int grow = nt * 128 + (lr >> 5) * 64 + i * 32 + (lr & 31);
            int gcol = mt * 128 + cg * 4;
            const int4 mi = *reinterpret_cast<const int4*>(mask + bI * SEQL + gcol);
            f32x4 v = *reinterpret_cast<const f32x4*>(&tl[lr][cg * 4]);
            float pads[4] = {(float)mi.x, (float)mi.y, (float)mi.z, (float)mi.w};
#pragma unroll
            for (int e = 0; e < 4; ++e) {
                float vv = v[e] * pads[e] - (1.0f - pads[e]) * NEGBIG;
                if (gcol + e < grow) vv -= NEGBIG;
                v[e] = vv * 0.125f;
            }
            __builtin_nontemporal_store(v, reinterpret_cast<f32x4*>(outbase + (size_t)grow * SEQL + gcol));
        }
        __syncthreads();
    }
}

extern "C" void kernel_launch(void* const* d_in, const int* in_sizes, int n_in,
                              void* d_out, int out_size, void* d_ws, size_t ws_size,
                              hipStream_t stream) {
    const float* x    = (const float*)d_in[0];
    const int*   mask = (const int*)d_in[1];
    const float* W    = (const float*)d_in[2];
    const float* bias = (const float*)d_in[3];
    float* out = (float*)d_out;

    char* ws = (char*)d_ws;
    unsigned short* Xbf = (unsigned short*)(ws);                 // 6,291,456 B
    unsigned short* Wbf = (unsigned short*)(ws + 6291456);       // 2,359,296 B
    unsigned short* Qbf = (unsigned short*)(ws + 8650752);       // 6,291,456 B
    unsigned short* Kbf = (unsigned short*)(ws + 14942208);      // 6,291,456 B
    float2*         rtab = (float2*)(ws + 21233664);             //   524,288 B

    const int prep_items = XQ + WQ + RQ;                         // 1,146,880
    k_prep<<<dim3((prep_items + 255) / 256), dim3(256), 0, stream>>>(x, W, Xbf, Wbf, rtab);
    k_proj_rope<<<dim3(384), dim3(256), 0, stream>>>(Xbf, Wbf, bias, rtab, Qbf, Kbf);
    k_logits<<<dim3(6144), dim3(256), 0, stream>>>(Qbf, Kbf, mask, out);
}

// Round 10
// 104.592 us; speedup vs baseline: 2.4996x; 1.1108x over previous
//
#include <hip/hip_runtime.h>
#include <hip/hip_bf16.h>
#include <cmath>

#define NH   12
#define HD   64
#define HID  768
#define NB   2
#define SEQL 2048
#define ROWS 4096   // NB*SEQL
#define OUTW 1536   // NH*HD*2

static constexpr float NEGBIG = 1000000000000.0f;

typedef __attribute__((ext_vector_type(4)))  float f32x4;
typedef __attribute__((ext_vector_type(8)))  short short8;
typedef __attribute__((ext_vector_type(16))) float f32x16;

__device__ __forceinline__ unsigned short f2bf(float f) {
    unsigned int u = __builtin_bit_cast(unsigned int, f);
    u += 0x7FFFu + ((u >> 16) & 1u);   // round-to-nearest-even
    return (unsigned short)(u >> 16);
}

// ---- K0: fused prep: convert X, convert W (f32->bf16), build rope table ----
#define XQ (ROWS * HID / 4)          // 786432 float4 groups
#define WQ (OUTW * HID / 4)          // 294912
#define RQ (SEQL * 32)               // 65536
__global__ void k_prep(const float* __restrict__ X, const float* __restrict__ W,
                       unsigned short* __restrict__ Xbf, unsigned short* __restrict__ Wbf,
                       float2* __restrict__ rtab) {
    int i = blockIdx.x * blockDim.x + threadIdx.x;
    if (i < XQ + WQ) {
        const float* src = (i < XQ) ? X : W;
        unsigned short* dst = (i < XQ) ? Xbf : Wbf;
        int k = (i < XQ) ? i : i - XQ;
        float4 v = reinterpret_cast<const float4*>(src)[k];
        ushort4 o;
        o.x = f2bf(v.x); o.y = f2bf(v.y); o.z = f2bf(v.z); o.w = f2bf(v.w);
        reinterpret_cast<ushort4*>(dst)[k] = o;
    } else if (i < XQ + WQ + RQ) {
        int idx = i - (XQ + WQ);
        int n = idx >> 5, d = idx & 31;
        float theta = exp2f(-(float)d * (13.287712379549449f / 32.0f)); // 10000^(-d/32)
        float ang = (float)n * theta;
        rtab[idx] = make_float2(sinf(ang), cosf(ang));
    }
}

// ---- K1: LDS-staged dbuf GEMM, 64x128 tile, 768 blocks (3/CU), bias-in-acc ----
__global__ __launch_bounds__(256, 3) void k_proj_rope(
    const unsigned short* __restrict__ Xbf,   // [4096][768] bf16
    const unsigned short* __restrict__ Wbf,   // [1536][768] bf16
    const float*  __restrict__ bias,          // [1536]
    const float2* __restrict__ rtab,          // [2048][32]
    unsigned short* __restrict__ Qbf,         // [2][12][2048][64] bf16
    unsigned short* __restrict__ Kbf)
{
    const int bid = blockIdx.x;                     // 0..767
    const int newbid = (bid & 7) * 96 + (bid >> 3); // bijective: 768 = 8*96
    const int slab = newbid / 12;                   // 0..63
    const int head = newbid % 12;                   // 0..11
    const int row0 = slab * 64;
    const int tid  = threadIdx.x;
    const int lane = tid & 63;
    const int w    = tid >> 6;
    const int wr = w & 1, wc = w >> 1;
    const int l31 = lane & 31, lhi = lane >> 5;
    const int x7  = l31 & 7;

    // 48 KB: A bufs [0,4096),[4096,8192); B bufs [8192,16384),[16384,24576) shorts
    __shared__ __align__(16) unsigned short smem[24576];

    // bias folded into accumulator init (C col = lane&31, constant per acc reg)
    f32x16 acc[2];
    {
        float bj0 = bias[head * 128 + wc * 64 + l31];
        float bj1 = bias[head * 128 + wc * 64 + 32 + l31];
#pragma unroll
        for (int r = 0; r < 16; ++r) { acc[0][r] = bj0; acc[1][r] = bj1; }
    }

    const unsigned short* Abase = Xbf + (size_t)row0 * HID;
    const unsigned short* Bbase = Wbf + (size_t)(head * 128) * HID;

    short8 ga[2], gb[4];
    // stage tile 0
#pragma unroll
    for (int r = 0; r < 2; ++r) {
        int idx = tid + 256 * r, row = idx >> 3, s = idx & 7;
        ga[r] = *reinterpret_cast<const short8*>(Abase + (size_t)row * HID + s * 8);
    }
#pragma unroll
    for (int r = 0; r < 4; ++r) {
        int idx = tid + 256 * r, row = idx >> 3, s = idx & 7;
        gb[r] = *reinterpret_cast<const short8*>(Bbase + (size_t)row * HID + s * 8);
    }
#pragma unroll
    for (int r = 0; r < 2; ++r) {
        int idx = tid + 256 * r, row = idx >> 3, s = idx & 7, ws = s ^ (row & 7);
        *reinterpret_cast<short8*>(smem + row * 64 + ws * 8) = ga[r];
    }
#pragma unroll
    for (int r = 0; r < 4; ++r) {
        int idx = tid + 256 * r, row = idx >> 3, s = idx & 7, ws = s ^ (row & 7);
        *reinterpret_cast<short8*>(smem + 8192 + row * 64 + ws * 8) = gb[r];
    }
    __syncthreads();

    for (int t = 0; t < 12; ++t) {
        const int cur = t & 1;
        if (t < 11) {
            const int kk = (t + 1) * 64;
#pragma unroll
            for (int r = 0; r < 2; ++r) {
                int idx = tid + 256 * r, row = idx >> 3, s = idx & 7;
                ga[r] = *reinterpret_cast<const short8*>(Abase + (size_t)row * HID + kk + s * 8);
            }
#pragma unroll
            for (int r = 0; r < 4; ++r) {
                int idx = tid + 256 * r, row = idx >> 3, s = idx & 7;
                gb[r] = *reinterpret_cast<const short8*>(Bbase + (size_t)row * HID + kk + s * 8);
            }
        }
        const unsigned short* Ab = smem + cur * 4096;
        const unsigned short* Bb = smem + 8192 + cur * 8192;
#pragma unroll
        for (int ks = 0; ks < 4; ++ks) {
            int sl = (ks * 2 + lhi) ^ x7;
            short8 a  = *reinterpret_cast<const short8*>(Ab + (wr * 32 + l31) * 64      + sl * 8);
            short8 b0 = *reinterpret_cast<const short8*>(Bb + (wc * 64 + l31) * 64      + sl * 8);
            short8 b1 = *reinterpret_cast<const short8*>(Bb + (wc * 64 + 32 + l31) * 64 + sl * 8);
            acc[0] = __builtin_amdgcn_mfma_f32_32x32x16_bf16(a, b0, acc[0], 0, 0, 0);
            acc[1] = __builtin_amdgcn_mfma_f32_32x32x16_bf16(a, b1, acc[1], 0, 0, 0);
        }
        if (t < 11) {
            const int nxt = cur ^ 1;
#pragma unroll
            for (int r = 0; r < 2; ++r) {
                int idx = tid + 256 * r, row = idx >> 3, s = idx & 7, ws = s ^ (row & 7);
                *reinterpret_cast<short8*>(smem + nxt * 4096 + row * 64 + ws * 8) = ga[r];
            }
#pragma unroll
            for (int r = 0; r < 4; ++r) {
                int idx = tid + 256 * r, row = idx >> 3, s = idx & 7, ws = s ^ (row & 7);
                *reinterpret_cast<short8*>(smem + 8192 + nxt * 8192 + row * 64 + ws * 8) = gb[r];
            }
        }
        __syncthreads();
    }

    // RoPE epilogue, single 64-row phase. hs cols: 0..63 = q, 64..127 = k (biased).
    float (*hs)[132] = reinterpret_cast<float (*)[132]>(smem);   // 33.8 KB < 48 KB
#pragma unroll
    for (int j = 0; j < 2; ++j)
#pragma unroll
        for (int r = 0; r < 16; ++r) {
            int rr = (r & 3) + 8 * (r >> 2) + 4 * lhi;  // 0..31
            hs[wr * 32 + rr][wc * 64 + j * 32 + l31] = acc[j][r];
        }
    __syncthreads();
    // 64 rows x 32 pairs x 2 (q,k) = 4096 ushort2 items, 16 per thread
#pragma unroll 4
    for (int it = 0; it < 16; ++it) {
        int f   = tid + 256 * it;    // 0..4095
        int row = f >> 6;            // 0..63
        int u   = f & 63;
        int isK = u >> 5;
        int dp  = u & 31;            // pair index
        int d0  = 2 * dp, d1 = d0 + 1;
        int cb  = isK * 64;
        int grow = row0 + row;
        int bI = grow >> 11;
        int n  = grow & 2047;
        float2 sc = rtab[n * 32 + dp];
        float v0 = hs[row][cb + d0];
        float v1 = hs[row][cb + d1];
        int p0 = (d0 < 32) ? (2 * d0 + 1) : (2 * d0 - 64);
        int p1 = (d1 < 32) ? (2 * d1 + 1) : (2 * d1 - 64);
        float pv0 = hs[row][cb + p0];
        float pv1 = hs[row][cb + p1];
        float sg0 = (d0 < 32) ? -1.0f : 1.0f;
        float sg1 = (d1 < 32) ? -1.0f : 1.0f;
        ushort2 st;
        st.x = f2bf(v0 * sc.y + sg0 * pv0 * sc.x);
        st.y = f2bf(v1 * sc.y + sg1 * pv1 * sc.x);
        unsigned short* dst = isK ? (unsigned short*)Kbf : (unsigned short*)Qbf;
        size_t idx = ((size_t)(bI * NH + head) * SEQL + n) * HD + d0;
        *reinterpret_cast<ushort2*>(dst + idx) = st;
    }
}

// ---- K2: logits = QK^T, mask + tril + scale, f32 out. 128x128 tile/block ----
// 1D grid with XCD-bijective swizzle: 6144 = 8 XCDs * 768; each XCD owns 3 bh.
__global__ __launch_bounds__(256) void k_logits(
    const unsigned short* __restrict__ Qbf,
    const unsigned short* __restrict__ Kbf,
    const int* __restrict__ mask,    // [2][2048]
    float* __restrict__ out)         // [2][12][2048][2048]
{
    const int bid = blockIdx.x;
    const int newbid = (bid & 7) * 768 + (bid >> 3);
    const int bh = newbid >> 8;
    const int t  = newbid & 255;
    const int nt = t >> 4, mt = t & 15;
    const int bI = bh / NH;
    const int tid = threadIdx.x;
    float* outbase = out + (size_t)bh * SEQL * SEQL;

    if (mt < nt) {
        // Tile entirely strictly-below-diagonal: output independent of logits.
        const int cg = tid & 31;        // column group -> 4 consecutive cols
        const int r0 = tid >> 5;        // 0..7
        const int m0 = mt * 128 + cg * 4;
        const int4 mi = *reinterpret_cast<const int4*>(mask + bI * SEQL + m0);
        f32x4 v;
        v.x = ((float)mi.x - 2.0f) * (NEGBIG * 0.125f);
        v.y = ((float)mi.y - 2.0f) * (NEGBIG * 0.125f);
        v.z = ((float)mi.z - 2.0f) * (NEGBIG * 0.125f);
        v.w = ((float)mi.w - 2.0f) * (NEGBIG * 0.125f);
        float* ob = outbase + (size_t)(nt * 128) * SEQL + m0;
#pragma unroll
        for (int j = 0; j < 16; ++j) {
            int row = r0 + 8 * j;       // 0..127
            __builtin_nontemporal_store(v, reinterpret_cast<f32x4*>(ob + (size_t)row * SEQL));
        }
        return;
    }

    const int lane = tid & 63;
    const int w = tid >> 6;
    const int rowHalf = w & 1, colHalf = w >> 1;
    const int l31 = lane & 31, lhi = lane >> 5;
    const int n0 = nt * 128 + rowHalf * 64;
    const int m0 = mt * 128 + colHalf * 64;

    f32x16 acc[2][2];
#pragma unroll
    for (int i = 0; i < 2; ++i)
#pragma unroll
        for (int j = 0; j < 2; ++j)
#pragma unroll
            for (int r = 0; r < 16; ++r) acc[i][j][r] = 0.0f;

    const unsigned short* Aq = Qbf + ((size_t)bh * SEQL + n0 + l31) * HD + 8 * lhi;
    const unsigned short* Bk = Kbf + ((size_t)bh * SEQL + m0 + l31) * HD + 8 * lhi;
#pragma unroll
    for (int t2 = 0; t2 < 4; ++t2) {
        short8 a0 = *reinterpret_cast<const short8*>(Aq + 16 * t2);
        short8 a1 = *reinterpret_cast<const short8*>(Aq + 32 * HD + 16 * t2);
        short8 b0 = *reinterpret_cast<const short8*>(Bk + 16 * t2);
        short8 b1 = *reinterpret_cast<const short8*>(Bk + 32 * HD + 16 * t2);
        acc[0][0] = __builtin_amdgcn_mfma_f32_32x32x16_bf16(a0, b0, acc[0][0], 0, 0, 0);
        acc[0][1] = __builtin_amdgcn_mfma_f32_32x32x16_bf16(a0, b1, acc[0][1], 0, 0, 0);
        acc[1][0] = __builtin_amdgcn_mfma_f32_32x32x16_bf16(a1, b0, acc[1][0], 0, 0, 0);
        acc[1][1] = __builtin_amdgcn_mfma_f32_32x32x16_bf16(a1, b1, acc[1][1], 0, 0, 0);
    }

    // LDS-transpose epilogue: two 32-row slabs (i = 0,1), f32x4 NT stores.
    __shared__ float tl[64][128];   // 32 KB
#pragma unroll
    for (int i = 0; i < 2; ++i) {
#pragma unroll
        for (int j = 0; j < 2; ++j) {
#pragma unroll
            for (int r = 0; r < 16; ++r) {
                int rr = (r & 3) + 8 * (r >> 2) + 4 * lhi;    // 0..31
                tl[rowHalf * 32 + rr][colHalf * 64 + j * 32 + l31] = acc[i][j][r];
            }
        }
        __syncthreads();
        // 64 rows x 128 cols = 2048 f32x4; 256 threads x 8 iters
#pragma unroll
        for (int it = 0; it < 8; ++it) {
            int f   = tid + 256 * it;      // 0..2047
            int lr  = f >> 5;              // 0..63
            int cg  = f & 31;              // 0..31 -> 4 cols
            int grow = nt * 128 + (lr >> 5) * 64 + i * 32 + (lr & 31);
            int gcol = mt * 128 + cg * 4;
            const int4 mi = *reinterpret_cast<const int4*>(mask + bI * SEQL + gcol);
            f32x4 v = *reinterpret_cast<const f32x4*>(&tl[lr][cg * 4]);
            float pads[4] = {(float)mi.x, (float)mi.y, (float)mi.z, (float)mi.w};
#pragma unroll
            for (int e = 0; e < 4; ++e) {
                float vv = v[e] * pads[e] - (1.0f - pads[e]) * NEGBIG;
                if (gcol + e < grow) vv -= NEGBIG;
                v[e] = vv * 0.125f;
            }
            __builtin_nontemporal_store(v, reinterpret_cast<f32x4*>(outbase + (size_t)grow * SEQL + gcol));
        }
        __syncthreads();
    }
}

extern "C" void kernel_launch(void* const* d_in, const int* in_sizes, int n_in,
                              void* d_out, int out_size, void* d_ws, size_t ws_size,
                              hipStream_t stream) {
    const float* x    = (const float*)d_in[0];
    const int*   mask = (const int*)d_in[1];
    const float* W    = (const float*)d_in[2];
    const float* bias = (const float*)d_in[3];
    float* out = (float*)d_out;

    char* ws = (char*)d_ws;
    unsigned short* Xbf = (unsigned short*)(ws);                 // 6,291,456 B
    unsigned short* Wbf = (unsigned short*)(ws + 6291456);       // 2,359,296 B
    unsigned short* Qbf = (unsigned short*)(ws + 8650752);       // 6,291,456 B
    unsigned short* Kbf = (unsigned short*)(ws + 14942208);      // 6,291,456 B
    float2*         rtab = (float2*)(ws + 21233664);             //   524,288 B

    const int prep_items = XQ + WQ + RQ;                         // 1,146,880
    k_prep<<<dim3((prep_items + 255) / 256), dim3(256), 0, stream>>>(x, W, Xbf, Wbf, rtab);
    k_proj_rope<<<dim3(768), dim3(256), 0, stream>>>(Xbf, Wbf, bias, rtab, Qbf, Kbf);
    k_logits<<<dim3(6144), dim3(256), 0, stream>>>(Qbf, Kbf, mask, out);
}